// Round 6
// baseline (277.669 us; speedup 1.0000x reference)
//
#include <hip/hip_runtime.h>
#include <stdint.h>

#define SIZE 65535

typedef __bf16 bf16x8 __attribute__((ext_vector_type(8)));
typedef __bf16 bf16x2 __attribute__((ext_vector_type(2)));
typedef float floatx4 __attribute__((ext_vector_type(4)));

// ws layout (bf16 elements), FRAGMENT-LINEAR: chunk = tile*64 + lane, 8 elems/chunk.
#define WS_ENCW 0        // [nt8][kt8][lane][8]        -> 32768
#define WS_WIH  32768    // [nt8][g3][kt4][lane][8]    -> 49152
#define WS_WHH  81920    // [nt8][g3][kt4][lane][8]    -> 49152
#define WS_VW   131072   // [nt4][kt4][lane][8]        -> 8192
#define WS_DECW 139264   // [kt6][lane][8] (rows>=10 zero) -> 3072
#define WS_TOTC 17792    // total chunks

__device__ __forceinline__ unsigned short f2bf(float f) {
    union { float f; unsigned int u; } v; v.f = f;
    unsigned int u = v.u;
    return (unsigned short)((u + 0x7fffu + ((u >> 16) & 1u)) >> 16);
}
__device__ __forceinline__ float bf2f(unsigned short b) {
    union { unsigned int u; float f; } v; v.u = ((unsigned int)b) << 16;
    return v.f;
}
__device__ __forceinline__ bf16x2 pk2(float a, float b) {
#if __has_builtin(__builtin_amdgcn_cvt_pk_bf16_f32)
    return __builtin_bit_cast(bf16x2, __builtin_amdgcn_cvt_pk_bf16_f32(a, b));
#else
    union { bf16x2 v; unsigned short s[2]; } r;
    r.s[0] = f2bf(a); r.s[1] = f2bf(b);
    return r.v;
#endif
}
__device__ __forceinline__ float sigmf(float x) {
    x = fminf(fmaxf(x, -30.f), 30.f);
    return 1.f / (1.f + __expf(-x));
}
__device__ __forceinline__ float tanhfast(float x) {
    x = fminf(fmaxf(x, -15.f), 15.f);
    float e = __expf(2.f * x);
    return (e - 1.f) / (e + 1.f);
}

union BF8 { bf16x8 v; bf16x2 p[4]; unsigned short s[8]; };

__device__ __forceinline__ bf16x8 cvt8g(const float* p) {
    float4 a = *reinterpret_cast<const float4*>(p);
    float4 b = *reinterpret_cast<const float4*>(p + 4);
    BF8 r;
    r.p[0] = pk2(a.x, a.y); r.p[1] = pk2(a.z, a.w);
    r.p[2] = pk2(b.x, b.y); r.p[3] = pk2(b.z, b.w);
    return r.v;
}
__device__ __forceinline__ bf16x8 ld8(const unsigned short* p) {
    return *reinterpret_cast<const bf16x8*>(p);
}

// ---------- pre-kernel: f32 weights -> bf16 fragment-linear layout ----------
__global__ __launch_bounds__(256) void cvt_weights(
    const float* __restrict__ enc_w, const float* __restrict__ w_ih,
    const float* __restrict__ w_hh, const float* __restrict__ v_w,
    const float* __restrict__ dec_w, unsigned short* __restrict__ ws) {
    int c = blockIdx.x * 256 + threadIdx.x;
    if (c >= WS_TOTC) return;
    const int lane = c & 63;
    const int l = lane & 15;
    const int q = lane >> 4;
    const float* src; int row, col, stride; bool zero = false;
    if (c < 4096) {                      // enc_w [nt8][kt8]
        int lt = c >> 6; int nt = lt >> 3, kt = lt & 7;
        row = nt * 16 + l; col = kt * 32 + q * 8; src = enc_w; stride = 256;
    } else if (c < 10240) {              // w_ih [nt8][g3][kt4]
        int lt = (c - 4096) >> 6; int nt = lt / 12; int r2 = lt % 12;
        int g = r2 >> 2, kt = r2 & 3;
        row = g * 128 + nt * 16 + l; col = kt * 32 + q * 8; src = w_ih; stride = 128;
    } else if (c < 16384) {              // w_hh
        int lt = (c - 10240) >> 6; int nt = lt / 12; int r2 = lt % 12;
        int g = r2 >> 2, kt = r2 & 3;
        row = g * 128 + nt * 16 + l; col = kt * 32 + q * 8; src = w_hh; stride = 128;
    } else if (c < 17408) {              // v_w [nt4][kt4]
        int lt = (c - 16384) >> 6; int nt = lt >> 2, kt = lt & 3;
        row = nt * 16 + l; col = kt * 32 + q * 8; src = v_w; stride = 128;
    } else {                             // dec_w [kt6], zero-pad rows 10..15
        int kt = (c - 17408) >> 6;
        row = l; col = kt * 32 + q * 8; src = dec_w; stride = 192;
        zero = (l >= 10);
    }
    float4 a, b;
    if (zero) { a = make_float4(0.f,0.f,0.f,0.f); b = a; }
    else {
        const float* p = src + (size_t)row * stride + col;
        a = *reinterpret_cast<const float4*>(p);
        b = *reinterpret_cast<const float4*>(p + 4);
    }
    unsigned short* d = ws + (size_t)c * 8;
    d[0]=f2bf(a.x); d[1]=f2bf(a.y); d[2]=f2bf(a.z); d[3]=f2bf(a.w);
    d[4]=f2bf(b.x); d[5]=f2bf(b.y); d[6]=f2bf(b.z); d[7]=f2bf(b.w);
}

// ---------- main fused kernel ----------
// Live subgraph only: enc -> GRU cell -> v -> dec.
// 512 blocks x 4 waves x 32 rows (m=2). Single 34.8 KB LDS buffer per block
// (x -> h_out -> v aliased in place) => 4 blocks/CU; VGPR<=128 => 16 waves/CU.
// dec is split: kt0..3 (h_out, from regs) accumulated BEFORE phase 3 so v can
// overwrite h_out's LDS cols 0..63.
__global__ __launch_bounds__(256, 4) void attn_critic_kernel(
    const float* __restrict__ obs,    // [SIZE,256] f32
    const float* __restrict__ hid,    // [SIZE,128] f32
    const float* __restrict__ enc_b,  // [128] f32
    const float* __restrict__ b_ih,   // [384] f32
    const float* __restrict__ b_hh,   // [384] f32
    const float* __restrict__ v_b,    // [64] f32
    const float* __restrict__ dec_b,  // [10] f32
    const unsigned short* __restrict__ wsw,  // bf16 fragment-linear weights
    float* __restrict__ out)          // [SIZE*10] ++ [SIZE*128] f32
{
    // stride 136 shorts = 272 B (16B-aligned; +4 banks/row => <=2-way, free)
    __shared__ __align__(16) unsigned short sA[4][32][136];  // 34816 B

    const int tid  = threadIdx.x;
    const int wave = tid >> 6;
    const int lane = tid & 63;
    const int l15  = lane & 15;
    const int quad = lane >> 4;
    const int wrow0 = (blockIdx.x * 4 + wave) * 32;

    int rA0 = wrow0 + l15;      rA0 = (rA0 < SIZE) ? rA0 : (SIZE - 1);
    int rA1 = wrow0 + 16 + l15; rA1 = (rA1 < SIZE) ? rA1 : (SIZE - 1);

    // ---- prefetch obs + hid A-fragments (one latency burst) ----
    bf16x8 aob[2][8], hf[2][4];
    {
        const float* o0 = obs + (size_t)rA0 * 256;
        const float* o1 = obs + (size_t)rA1 * 256;
#pragma unroll
        for (int kt = 0; kt < 8; ++kt) {
            aob[0][kt] = cvt8g(o0 + kt * 32 + quad * 8);
            aob[1][kt] = cvt8g(o1 + kt * 32 + quad * 8);
        }
        const float* h0 = hid + (size_t)rA0 * 128;
        const float* h1 = hid + (size_t)rA1 * 128;
#pragma unroll
        for (int kt = 0; kt < 4; ++kt) {
            hf[0][kt] = cvt8g(h0 + kt * 32 + quad * 8);
            hf[1][kt] = cvt8g(h1 + kt * 32 + quad * 8);
        }
    }
    __builtin_amdgcn_sched_barrier(0);

    // ---- Phase 1: X = relu(OBS @ enc_w^T + enc_b) -> sA cols 0..127 ----
    {
        const unsigned short* encf = wsw + WS_ENCW + lane * 8;
#pragma unroll 2
        for (int nt = 0; nt < 8; ++nt) {
            floatx4 a0 = floatx4{0.f,0.f,0.f,0.f}, a1 = a0;
#pragma unroll
            for (int kt = 0; kt < 8; ++kt) {
                bf16x8 b = ld8(encf + (size_t)(nt * 8 + kt) * 512);
                a0 = __builtin_amdgcn_mfma_f32_16x16x32_bf16(aob[0][kt], b, a0, 0, 0, 0);
                a1 = __builtin_amdgcn_mfma_f32_16x16x32_bf16(aob[1][kt], b, a1, 0, 0, 0);
            }
            float bias = enc_b[nt * 16 + l15];
#pragma unroll
            for (int r = 0; r < 4; ++r) {
                sA[wave][quad * 4 + r][nt * 16 + l15]      = f2bf(fmaxf(a0[r] + bias, 0.f));
                sA[wave][16 + quad * 4 + r][nt * 16 + l15] = f2bf(fmaxf(a1[r] + bias, 0.f));
            }
        }
    }
    bf16x8 xf[2][4];
#pragma unroll
    for (int kt = 0; kt < 4; ++kt) {
        xf[0][kt] = ld8(&sA[wave][l15][kt * 32 + quad * 8]);
        xf[1][kt] = ld8(&sA[wave][16 + l15][kt * 32 + quad * 8]);
    }

    // ---- Phase 2: GRU cell (h_out bf16 overwrites x in sA cols 0..127) ----
    {
        const unsigned short* wihf = wsw + WS_WIH + lane * 8;
        const unsigned short* whhf = wsw + WS_WHH + lane * 8;
#pragma unroll 1
        for (int nt = 0; nt < 8; ++nt) {
            const int nr = nt * 16 + l15;
            floatx4 gi[3][2], gh[3][2];
#pragma unroll
            for (int g = 0; g < 3; ++g) {
                gi[g][0] = floatx4{0.f,0.f,0.f,0.f}; gi[g][1] = gi[g][0];
                gh[g][0] = gi[g][0]; gh[g][1] = gi[g][0];
            }
#pragma unroll
            for (int g = 0; g < 3; ++g)
#pragma unroll
                for (int kt = 0; kt < 4; ++kt) {
                    bf16x8 bi = ld8(wihf + (size_t)((nt * 3 + g) * 4 + kt) * 512);
                    bf16x8 bh = ld8(whhf + (size_t)((nt * 3 + g) * 4 + kt) * 512);
                    gi[g][0] = __builtin_amdgcn_mfma_f32_16x16x32_bf16(xf[0][kt], bi, gi[g][0], 0, 0, 0);
                    gi[g][1] = __builtin_amdgcn_mfma_f32_16x16x32_bf16(xf[1][kt], bi, gi[g][1], 0, 0, 0);
                    gh[g][0] = __builtin_amdgcn_mfma_f32_16x16x32_bf16(hf[0][kt], bh, gh[g][0], 0, 0, 0);
                    gh[g][1] = __builtin_amdgcn_mfma_f32_16x16x32_bf16(hf[1][kt], bh, gh[g][1], 0, 0, 0);
                }
            const float bir_ = b_ih[nr], biz_ = b_ih[nr + 128], bin_ = b_ih[nr + 256];
            const float bhr_ = b_hh[nr], bhz_ = b_hh[nr + 128], bhn_ = b_hh[nr + 256];
#pragma unroll
            for (int m = 0; m < 2; ++m)
#pragma unroll
                for (int r = 0; r < 4; ++r) {
                    const int grow = wrow0 + m * 16 + quad * 4 + r;
                    const int rowc = (grow < SIZE) ? grow : (SIZE - 1);
                    float hprev = hid[(size_t)rowc * 128 + nr];
                    float rg = sigmf(gi[0][m][r] + bir_ + gh[0][m][r] + bhr_);
                    float zg = sigmf(gi[1][m][r] + biz_ + gh[1][m][r] + bhz_);
                    float ng = tanhfast(gi[2][m][r] + bin_ + rg * (gh[2][m][r] + bhn_));
                    float ho = (1.f - zg) * ng + zg * hprev;
                    sA[wave][m * 16 + quad * 4 + r][nr] = f2bf(ho);
                }
        }
    }

    // h_out A-fragments (needed for v, dec-part-a)
    bf16x8 af[2][4];
#pragma unroll
    for (int kt = 0; kt < 4; ++kt) {
        af[0][kt] = ld8(&sA[wave][l15][kt * 32 + quad * 8]);
        af[1][kt] = ld8(&sA[wave][16 + l15][kt * 32 + quad * 8]);
    }

    // ---- h_out -> global, coalesced (full lines, float2 8B-aligned) ----
    {
        float* out_h = out + (size_t)SIZE * 10;
#pragma unroll 1
        for (int it = 0; it < 16; ++it) {
            int idx = it * 256 + lane * 4;   // over [32][128]
            int rr = idx >> 7, cc = idx & 127;
            int grow = wrow0 + rr;
            if (grow < SIZE) {
                float2 p0 = make_float2(bf2f(sA[wave][rr][cc]),     bf2f(sA[wave][rr][cc + 1]));
                float2 p1 = make_float2(bf2f(sA[wave][rr][cc + 2]), bf2f(sA[wave][rr][cc + 3]));
                float* dst = out_h + (size_t)grow * 128 + cc;
                *reinterpret_cast<float2*>(dst)     = p0;
                *reinterpret_cast<float2*>(dst + 2) = p1;
            }
        }
    }

    // ---- Phase 4a: dec contribution of h_out (kt 0..3), from registers ----
    const unsigned short* decf = wsw + WS_DECW + lane * 8;
    floatx4 d0 = floatx4{0.f,0.f,0.f,0.f}, d1 = d0;
#pragma unroll
    for (int kt = 0; kt < 4; ++kt) {
        bf16x8 b = ld8(decf + (size_t)kt * 512);
        d0 = __builtin_amdgcn_mfma_f32_16x16x32_bf16(af[0][kt], b, d0, 0, 0, 0);
        d1 = __builtin_amdgcn_mfma_f32_16x16x32_bf16(af[1][kt], b, d1, 0, 0, 0);
    }

    // ---- Phase 3: V = relu(H_OUT @ v_w^T + v_b) -> sA cols 0..63 ----
    // (h_out LDS copy is dead: af in regs, global store done, dec kt0..3 done)
    {
        const unsigned short* vwf = wsw + WS_VW + lane * 8;
#pragma unroll 1
        for (int nt = 0; nt < 4; ++nt) {
            floatx4 a0 = floatx4{0.f,0.f,0.f,0.f}, a1 = a0;
#pragma unroll
            for (int kt = 0; kt < 4; ++kt) {
                bf16x8 b = ld8(vwf + (size_t)(nt * 4 + kt) * 512);
                a0 = __builtin_amdgcn_mfma_f32_16x16x32_bf16(af[0][kt], b, a0, 0, 0, 0);
                a1 = __builtin_amdgcn_mfma_f32_16x16x32_bf16(af[1][kt], b, a1, 0, 0, 0);
            }
            float bias = v_b[nt * 16 + l15];
#pragma unroll
            for (int r = 0; r < 4; ++r) {
                sA[wave][quad * 4 + r][nt * 16 + l15]      = f2bf(fmaxf(a0[r] + bias, 0.f));
                sA[wave][16 + quad * 4 + r][nt * 16 + l15] = f2bf(fmaxf(a1[r] + bias, 0.f));
            }
        }
    }

    // ---- Phase 4b: dec contribution of v (kt 4..5) + store logits ----
    {
#pragma unroll
        for (int kt = 4; kt < 6; ++kt) {
            bf16x8 b  = ld8(decf + (size_t)kt * 512);
            bf16x8 a0 = ld8(&sA[wave][l15][(kt - 4) * 32 + quad * 8]);
            bf16x8 a1 = ld8(&sA[wave][16 + l15][(kt - 4) * 32 + quad * 8]);
            d0 = __builtin_amdgcn_mfma_f32_16x16x32_bf16(a0, b, d0, 0, 0, 0);
            d1 = __builtin_amdgcn_mfma_f32_16x16x32_bf16(a1, b, d1, 0, 0, 0);
        }
        if (l15 < 10) {
            float bias = dec_b[l15];
#pragma unroll
            for (int r = 0; r < 4; ++r) {
                int g0 = wrow0 + quad * 4 + r;
                int g1 = g0 + 16;
                if (g0 < SIZE) out[(size_t)g0 * 10 + l15] = d0[r] + bias;
                if (g1 < SIZE) out[(size_t)g1 * 10 + l15] = d1[r] + bias;
            }
        }
    }
}

extern "C" void kernel_launch(void* const* d_in, const int* in_sizes, int n_in,
                              void* d_out, int out_size, void* d_ws, size_t ws_size,
                              hipStream_t stream) {
    const float* obs   = (const float*)d_in[0];
    const float* hid   = (const float*)d_in[1];
    const float* enc_w = (const float*)d_in[2];
    const float* enc_b = (const float*)d_in[3];
    const float* w_ih  = (const float*)d_in[4];
    const float* w_hh  = (const float*)d_in[5];
    const float* b_ih  = (const float*)d_in[6];
    const float* b_hh  = (const float*)d_in[7];
    // d_in[8..19]: dead code (bi-GRU / hard attention / q,k) — unused.
    const float* v_w   = (const float*)d_in[20];
    const float* v_b   = (const float*)d_in[21];
    const float* dec_w = (const float*)d_in[22];
    const float* dec_b = (const float*)d_in[23];
    unsigned short* wsw = (unsigned short*)d_ws;
    float* out = (float*)d_out;

    hipLaunchKernelGGL(cvt_weights, dim3((WS_TOTC + 255) / 256), dim3(256), 0, stream,
                       enc_w, w_ih, w_hh, v_w, dec_w, wsw);
    // 512 blocks x 4 waves x 32 rows = 65536 >= 65535
    hipLaunchKernelGGL(attn_critic_kernel, dim3(512), dim3(256), 0, stream,
                       obs, hid, enc_b, b_ih, b_hh, v_b, dec_b, wsw, out);
}

// Round 7
// 223.937 us; speedup vs baseline: 1.2399x; 1.2399x over previous
//
#include <hip/hip_runtime.h>
#include <stdint.h>

#define SIZE 65535

typedef __bf16 bf16x8 __attribute__((ext_vector_type(8)));
typedef __bf16 bf16x2 __attribute__((ext_vector_type(2)));
typedef float floatx4 __attribute__((ext_vector_type(4)));

// ws layout (bf16 elements), FRAGMENT-LINEAR: chunk = tile*64 + lane, 8 elems/chunk.
#define WS_ENCW 0        // [nt8][kt8][lane][8]        -> 32768
#define WS_WIH  32768    // [nt8][g3][kt4][lane][8]    -> 49152
#define WS_WHH  81920    // [nt8][g3][kt4][lane][8]    -> 49152
#define WS_VW   131072   // [nt4][kt4][lane][8]        -> 8192
#define WS_DECW 139264   // [kt6][lane][8] (rows>=10 zero) -> 3072
#define WS_TOTC 17792    // total chunks

__device__ __forceinline__ unsigned short f2bf(float f) {
    union { float f; unsigned int u; } v; v.f = f;
    unsigned int u = v.u;
    return (unsigned short)((u + 0x7fffu + ((u >> 16) & 1u)) >> 16);
}
__device__ __forceinline__ float bf2f(unsigned short b) {
    union { unsigned int u; float f; } v; v.u = ((unsigned int)b) << 16;
    return v.f;
}
__device__ __forceinline__ bf16x2 pk2(float a, float b) {
#if __has_builtin(__builtin_amdgcn_cvt_pk_bf16_f32)
    return __builtin_bit_cast(bf16x2, __builtin_amdgcn_cvt_pk_bf16_f32(a, b));
#else
    union { bf16x2 v; unsigned short s[2]; } r;
    r.s[0] = f2bf(a); r.s[1] = f2bf(b);
    return r.v;
#endif
}
__device__ __forceinline__ float sigmf(float x) {
    x = fminf(fmaxf(x, -30.f), 30.f);
    return 1.f / (1.f + __expf(-x));
}
__device__ __forceinline__ float tanhfast(float x) {
    x = fminf(fmaxf(x, -15.f), 15.f);
    float e = __expf(2.f * x);
    return (e - 1.f) / (e + 1.f);
}

union BF8 { bf16x8 v; bf16x2 p[4]; unsigned short s[8]; };

__device__ __forceinline__ bf16x8 cvt8g(const float* p) {
    float4 a = *reinterpret_cast<const float4*>(p);
    float4 b = *reinterpret_cast<const float4*>(p + 4);
    BF8 r;
    r.p[0] = pk2(a.x, a.y); r.p[1] = pk2(a.z, a.w);
    r.p[2] = pk2(b.x, b.y); r.p[3] = pk2(b.z, b.w);
    return r.v;
}
__device__ __forceinline__ bf16x8 ld8(const unsigned short* p) {
    return *reinterpret_cast<const bf16x8*>(p);
}

// ---------- pre-kernel: f32 weights -> bf16 fragment-linear layout ----------
__global__ __launch_bounds__(256) void cvt_weights(
    const float* __restrict__ enc_w, const float* __restrict__ w_ih,
    const float* __restrict__ w_hh, const float* __restrict__ v_w,
    const float* __restrict__ dec_w, unsigned short* __restrict__ ws) {
    int c = blockIdx.x * 256 + threadIdx.x;
    if (c >= WS_TOTC) return;
    const int lane = c & 63;
    const int l = lane & 15;
    const int q = lane >> 4;
    const float* src; int row, col, stride; bool zero = false;
    if (c < 4096) {                      // enc_w [nt8][kt8]
        int lt = c >> 6; int nt = lt >> 3, kt = lt & 7;
        row = nt * 16 + l; col = kt * 32 + q * 8; src = enc_w; stride = 256;
    } else if (c < 10240) {              // w_ih [nt8][g3][kt4]
        int lt = (c - 4096) >> 6; int nt = lt / 12; int r2 = lt % 12;
        int g = r2 >> 2, kt = r2 & 3;
        row = g * 128 + nt * 16 + l; col = kt * 32 + q * 8; src = w_ih; stride = 128;
    } else if (c < 16384) {              // w_hh
        int lt = (c - 10240) >> 6; int nt = lt / 12; int r2 = lt % 12;
        int g = r2 >> 2, kt = r2 & 3;
        row = g * 128 + nt * 16 + l; col = kt * 32 + q * 8; src = w_hh; stride = 128;
    } else if (c < 17408) {              // v_w [nt4][kt4]
        int lt = (c - 16384) >> 6; int nt = lt >> 2, kt = lt & 3;
        row = nt * 16 + l; col = kt * 32 + q * 8; src = v_w; stride = 128;
    } else {                             // dec_w [kt6], zero-pad rows 10..15
        int kt = (c - 17408) >> 6;
        row = l; col = kt * 32 + q * 8; src = dec_w; stride = 192;
        zero = (l >= 10);
    }
    float4 a, b;
    if (zero) { a = make_float4(0.f,0.f,0.f,0.f); b = a; }
    else {
        const float* p = src + (size_t)row * stride + col;
        a = *reinterpret_cast<const float4*>(p);
        b = *reinterpret_cast<const float4*>(p + 4);
    }
    unsigned short* d = ws + (size_t)c * 8;
    d[0]=f2bf(a.x); d[1]=f2bf(a.y); d[2]=f2bf(a.z); d[3]=f2bf(a.w);
    d[4]=f2bf(b.x); d[5]=f2bf(b.y); d[6]=f2bf(b.z); d[7]=f2bf(b.w);
}

// ---------- main fused kernel ----------
// Live subgraph only: enc -> GRU cell -> v -> dec.
// 512 blocks x 4 waves x 32 rows (m=2). Single 34.8 KB LDS buffer per block
// (x -> h_out -> v aliased in place) => 4 blocks/CU by LDS.
// launch_bounds(256,2): round 5 showed the allocator then lands at ~124 VGPR
// (<=128 => HW runs 4 waves/SIMD anyway); (256,4) in round 6 forced a bad
// 64-reg tier with massive scratch spills (FETCH/WRITE +100 MB). The 2nd arg
// constrains the allocator, not achieved occupancy — keep it loose.
__global__ __launch_bounds__(256, 2) void attn_critic_kernel(
    const float* __restrict__ obs,    // [SIZE,256] f32
    const float* __restrict__ hid,    // [SIZE,128] f32
    const float* __restrict__ enc_b,  // [128] f32
    const float* __restrict__ b_ih,   // [384] f32
    const float* __restrict__ b_hh,   // [384] f32
    const float* __restrict__ v_b,    // [64] f32
    const float* __restrict__ dec_b,  // [10] f32
    const unsigned short* __restrict__ wsw,  // bf16 fragment-linear weights
    float* __restrict__ out)          // [SIZE*10] ++ [SIZE*128] f32
{
    // stride 136 shorts = 272 B (16B-aligned; +4 banks/row => <=2-way, free)
    __shared__ __align__(16) unsigned short sA[4][32][136];  // 34816 B

    const int tid  = threadIdx.x;
    const int wave = tid >> 6;
    const int lane = tid & 63;
    const int l15  = lane & 15;
    const int quad = lane >> 4;
    const int wrow0 = (blockIdx.x * 4 + wave) * 32;

    int rA0 = wrow0 + l15;      rA0 = (rA0 < SIZE) ? rA0 : (SIZE - 1);
    int rA1 = wrow0 + 16 + l15; rA1 = (rA1 < SIZE) ? rA1 : (SIZE - 1);

    // ---- prefetch obs + hid A-fragments (one latency burst) ----
    bf16x8 aob[2][8], hf[2][4];
    {
        const float* o0 = obs + (size_t)rA0 * 256;
        const float* o1 = obs + (size_t)rA1 * 256;
#pragma unroll
        for (int kt = 0; kt < 8; ++kt) {
            aob[0][kt] = cvt8g(o0 + kt * 32 + quad * 8);
            aob[1][kt] = cvt8g(o1 + kt * 32 + quad * 8);
        }
        const float* h0 = hid + (size_t)rA0 * 128;
        const float* h1 = hid + (size_t)rA1 * 128;
#pragma unroll
        for (int kt = 0; kt < 4; ++kt) {
            hf[0][kt] = cvt8g(h0 + kt * 32 + quad * 8);
            hf[1][kt] = cvt8g(h1 + kt * 32 + quad * 8);
        }
    }
    __builtin_amdgcn_sched_barrier(0);

    // ---- Phase 1: X = relu(OBS @ enc_w^T + enc_b) -> sA cols 0..127 ----
    {
        const unsigned short* encf = wsw + WS_ENCW + lane * 8;
#pragma unroll 2
        for (int nt = 0; nt < 8; ++nt) {
            floatx4 a0 = floatx4{0.f,0.f,0.f,0.f}, a1 = a0;
#pragma unroll
            for (int kt = 0; kt < 8; ++kt) {
                bf16x8 b = ld8(encf + (size_t)(nt * 8 + kt) * 512);
                a0 = __builtin_amdgcn_mfma_f32_16x16x32_bf16(aob[0][kt], b, a0, 0, 0, 0);
                a1 = __builtin_amdgcn_mfma_f32_16x16x32_bf16(aob[1][kt], b, a1, 0, 0, 0);
            }
            float bias = enc_b[nt * 16 + l15];
#pragma unroll
            for (int r = 0; r < 4; ++r) {
                sA[wave][quad * 4 + r][nt * 16 + l15]      = f2bf(fmaxf(a0[r] + bias, 0.f));
                sA[wave][16 + quad * 4 + r][nt * 16 + l15] = f2bf(fmaxf(a1[r] + bias, 0.f));
            }
        }
    }
    bf16x8 xf[2][4];
#pragma unroll
    for (int kt = 0; kt < 4; ++kt) {
        xf[0][kt] = ld8(&sA[wave][l15][kt * 32 + quad * 8]);
        xf[1][kt] = ld8(&sA[wave][16 + l15][kt * 32 + quad * 8]);
    }

    // ---- Phase 2: GRU cell (h_out bf16 overwrites x in sA cols 0..127) ----
    {
        const unsigned short* wihf = wsw + WS_WIH + lane * 8;
        const unsigned short* whhf = wsw + WS_WHH + lane * 8;
#pragma unroll 1
        for (int nt = 0; nt < 8; ++nt) {
            const int nr = nt * 16 + l15;
            floatx4 gi[3][2], gh[3][2];
#pragma unroll
            for (int g = 0; g < 3; ++g) {
                gi[g][0] = floatx4{0.f,0.f,0.f,0.f}; gi[g][1] = gi[g][0];
                gh[g][0] = gi[g][0]; gh[g][1] = gi[g][0];
            }
#pragma unroll
            for (int g = 0; g < 3; ++g)
#pragma unroll
                for (int kt = 0; kt < 4; ++kt) {
                    bf16x8 bi = ld8(wihf + (size_t)((nt * 3 + g) * 4 + kt) * 512);
                    bf16x8 bh = ld8(whhf + (size_t)((nt * 3 + g) * 4 + kt) * 512);
                    gi[g][0] = __builtin_amdgcn_mfma_f32_16x16x32_bf16(xf[0][kt], bi, gi[g][0], 0, 0, 0);
                    gi[g][1] = __builtin_amdgcn_mfma_f32_16x16x32_bf16(xf[1][kt], bi, gi[g][1], 0, 0, 0);
                    gh[g][0] = __builtin_amdgcn_mfma_f32_16x16x32_bf16(hf[0][kt], bh, gh[g][0], 0, 0, 0);
                    gh[g][1] = __builtin_amdgcn_mfma_f32_16x16x32_bf16(hf[1][kt], bh, gh[g][1], 0, 0, 0);
                }
            const float bir_ = b_ih[nr], biz_ = b_ih[nr + 128], bin_ = b_ih[nr + 256];
            const float bhr_ = b_hh[nr], bhz_ = b_hh[nr + 128], bhn_ = b_hh[nr + 256];
#pragma unroll
            for (int m = 0; m < 2; ++m)
#pragma unroll
                for (int r = 0; r < 4; ++r) {
                    const int grow = wrow0 + m * 16 + quad * 4 + r;
                    const int rowc = (grow < SIZE) ? grow : (SIZE - 1);
                    float hprev = hid[(size_t)rowc * 128 + nr];
                    float rg = sigmf(gi[0][m][r] + bir_ + gh[0][m][r] + bhr_);
                    float zg = sigmf(gi[1][m][r] + biz_ + gh[1][m][r] + bhz_);
                    float ng = tanhfast(gi[2][m][r] + bin_ + rg * (gh[2][m][r] + bhn_));
                    float ho = (1.f - zg) * ng + zg * hprev;
                    sA[wave][m * 16 + quad * 4 + r][nr] = f2bf(ho);
                }
        }
    }

    // h_out A-fragments (needed for v, dec-part-a)
    bf16x8 af[2][4];
#pragma unroll
    for (int kt = 0; kt < 4; ++kt) {
        af[0][kt] = ld8(&sA[wave][l15][kt * 32 + quad * 8]);
        af[1][kt] = ld8(&sA[wave][16 + l15][kt * 32 + quad * 8]);
    }

    // ---- h_out -> global, coalesced (full lines, float2 8B-aligned) ----
    {
        float* out_h = out + (size_t)SIZE * 10;
#pragma unroll 1
        for (int it = 0; it < 16; ++it) {
            int idx = it * 256 + lane * 4;   // over [32][128]
            int rr = idx >> 7, cc = idx & 127;
            int grow = wrow0 + rr;
            if (grow < SIZE) {
                float2 p0 = make_float2(bf2f(sA[wave][rr][cc]),     bf2f(sA[wave][rr][cc + 1]));
                float2 p1 = make_float2(bf2f(sA[wave][rr][cc + 2]), bf2f(sA[wave][rr][cc + 3]));
                float* dst = out_h + (size_t)grow * 128 + cc;
                *reinterpret_cast<float2*>(dst)     = p0;
                *reinterpret_cast<float2*>(dst + 2) = p1;
            }
        }
    }

    // ---- Phase 4a: dec contribution of h_out (kt 0..3), from registers ----
    const unsigned short* decf = wsw + WS_DECW + lane * 8;
    floatx4 d0 = floatx4{0.f,0.f,0.f,0.f}, d1 = d0;
#pragma unroll
    for (int kt = 0; kt < 4; ++kt) {
        bf16x8 b = ld8(decf + (size_t)kt * 512);
        d0 = __builtin_amdgcn_mfma_f32_16x16x32_bf16(af[0][kt], b, d0, 0, 0, 0);
        d1 = __builtin_amdgcn_mfma_f32_16x16x32_bf16(af[1][kt], b, d1, 0, 0, 0);
    }

    // ---- Phase 3: V = relu(H_OUT @ v_w^T + v_b) -> sA cols 0..63 ----
    // (h_out LDS copy is dead: af in regs, global store done, dec kt0..3 done)
    {
        const unsigned short* vwf = wsw + WS_VW + lane * 8;
#pragma unroll 1
        for (int nt = 0; nt < 4; ++nt) {
            floatx4 a0 = floatx4{0.f,0.f,0.f,0.f}, a1 = a0;
#pragma unroll
            for (int kt = 0; kt < 4; ++kt) {
                bf16x8 b = ld8(vwf + (size_t)(nt * 4 + kt) * 512);
                a0 = __builtin_amdgcn_mfma_f32_16x16x32_bf16(af[0][kt], b, a0, 0, 0, 0);
                a1 = __builtin_amdgcn_mfma_f32_16x16x32_bf16(af[1][kt], b, a1, 0, 0, 0);
            }
            float bias = v_b[nt * 16 + l15];
#pragma unroll
            for (int r = 0; r < 4; ++r) {
                sA[wave][quad * 4 + r][nt * 16 + l15]      = f2bf(fmaxf(a0[r] + bias, 0.f));
                sA[wave][16 + quad * 4 + r][nt * 16 + l15] = f2bf(fmaxf(a1[r] + bias, 0.f));
            }
        }
    }

    // ---- Phase 4b: dec contribution of v (kt 4..5) + store logits ----
    {
#pragma unroll
        for (int kt = 4; kt < 6; ++kt) {
            bf16x8 b  = ld8(decf + (size_t)kt * 512);
            bf16x8 a0 = ld8(&sA[wave][l15][(kt - 4) * 32 + quad * 8]);
            bf16x8 a1 = ld8(&sA[wave][16 + l15][(kt - 4) * 32 + quad * 8]);
            d0 = __builtin_amdgcn_mfma_f32_16x16x32_bf16(a0, b, d0, 0, 0, 0);
            d1 = __builtin_amdgcn_mfma_f32_16x16x32_bf16(a1, b, d1, 0, 0, 0);
        }
        if (l15 < 10) {
            float bias = dec_b[l15];
#pragma unroll
            for (int r = 0; r < 4; ++r) {
                int g0 = wrow0 + quad * 4 + r;
                int g1 = g0 + 16;
                if (g0 < SIZE) out[(size_t)g0 * 10 + l15] = d0[r] + bias;
                if (g1 < SIZE) out[(size_t)g1 * 10 + l15] = d1[r] + bias;
            }
        }
    }
}

extern "C" void kernel_launch(void* const* d_in, const int* in_sizes, int n_in,
                              void* d_out, int out_size, void* d_ws, size_t ws_size,
                              hipStream_t stream) {
    const float* obs   = (const float*)d_in[0];
    const float* hid   = (const float*)d_in[1];
    const float* enc_w = (const float*)d_in[2];
    const float* enc_b = (const float*)d_in[3];
    const float* w_ih  = (const float*)d_in[4];
    const float* w_hh  = (const float*)d_in[5];
    const float* b_ih  = (const float*)d_in[6];
    const float* b_hh  = (const float*)d_in[7];
    // d_in[8..19]: dead code (bi-GRU / hard attention / q,k) — unused.
    const float* v_w   = (const float*)d_in[20];
    const float* v_b   = (const float*)d_in[21];
    const float* dec_w = (const float*)d_in[22];
    const float* dec_b = (const float*)d_in[23];
    unsigned short* wsw = (unsigned short*)d_ws;
    float* out = (float*)d_out;

    hipLaunchKernelGGL(cvt_weights, dim3((WS_TOTC + 255) / 256), dim3(256), 0, stream,
                       enc_w, w_ih, w_hh, v_w, dec_w, wsw);
    // 512 blocks x 4 waves x 32 rows = 65536 >= 65535
    hipLaunchKernelGGL(attn_critic_kernel, dim3(512), dim3(256), 0, stream,
                       obs, hid, enc_b, b_ih, b_hh, v_b, dec_b, wsw, out);
}